// Round 4
// baseline (454.150 us; speedup 1.0000x reference)
//
#include <hip/hip_runtime.h>
#include <hip/hip_fp16.h>

typedef float fv4 __attribute__((ext_vector_type(4)));
using hf8   = __attribute__((ext_vector_type(8))) _Float16;  // 8 fp16 = 4 VGPRs (MFMA A/B frag)
using f32x4 = __attribute__((ext_vector_type(4))) float;     // MFMA C/D frag
using u32x4 = __attribute__((ext_vector_type(4))) unsigned;

#define HDIM 64

// fp32 -> fp16 bits (RNE)
__device__ __forceinline__ unsigned short f16r(float f) {
    return __half_as_ushort(__float2half(f));
}
__device__ __forceinline__ float hs2f(unsigned short s) {
    return __half2float(__ushort_as_half(s));
}
// packed fp16: relu(u+v) on 2 channels in one reg.
// ROCm 7.2 headers lack a __hmax2(__half2,__half2) overload -> emit the two
// packed VALU ops directly (v_pk_add_f16 + v_pk_max_f16 with inline 0).
__device__ __forceinline__ unsigned addrelu2(unsigned ua, unsigned va) {
    unsigned s, r;
    asm("v_pk_add_f16 %0, %1, %2" : "=v"(s) : "v"(ua), "v"(va));
    asm("v_pk_max_f16 %0, %1, 0" : "=v"(r) : "v"(s));
    return r;
}

// ---------------------------------------------------------------------------
// prep: (a) split W2 of conv1/conv2 into transposed fp16 hi/lo  [c][j]
//       (b) build combined pre-GEMM weight for conv2:
//           Wpre[c'][d], c'<64: (W1a-W1b)^T (U part), c'>=64: W1b^T (V part)
// fp16 hi+lo recovers ~22 mantissa bits -> no systematic weight-quant error.
// ---------------------------------------------------------------------------
__global__ void prep_kernel(const float* __restrict__ W2a, const float* __restrict__ W2b,
                            const float* __restrict__ W1c,
                            unsigned short* __restrict__ hiA, unsigned short* __restrict__ loA,
                            unsigned short* __restrict__ hiB, unsigned short* __restrict__ loB,
                            unsigned short* __restrict__ wph, unsigned short* __restrict__ wpl)
{
    int idx = blockIdx.x * 256 + threadIdx.x;
    if (idx < 4096) {
        int j = idx >> 6, c = idx & 63;
        float w = W2a[idx];
        unsigned short h = f16r(w);
        unsigned short l = f16r(w - hs2f(h));
        hiA[c * 64 + j] = h; loA[c * 64 + j] = l;
        w = W2b[idx];
        h = f16r(w);
        l = f16r(w - hs2f(h));
        hiB[c * 64 + j] = h; loB[c * 64 + j] = l;
    }
    if (idx < 8192) {
        int d = idx & 63, cp = idx >> 6;
        float w = (cp < 64) ? (W1c[d * 64 + cp] - W1c[(d + 64) * 64 + cp])
                            : W1c[(d + 64) * 64 + (cp - 64)];
        unsigned short h = f16r(w);
        unsigned short l = f16r(w - hs2f(h));
        wph[cp * 64 + d] = h;
        wpl[cp * 64 + d] = l;
    }
}

// ---------------------------------------------------------------------------
// pre1: u = [x|pos] @ (W1a - W1b) + b1 ; v = [x|pos] @ W1b   (D = 19)
// fp32 math, fp16 outputs.
// ---------------------------------------------------------------------------
__global__ void pre1_kernel(
    const float* __restrict__ x, const float* __restrict__ pos,
    const float* __restrict__ W1, const float* __restrict__ b1,
    unsigned short* __restrict__ U, unsigned short* __restrict__ V, int N)
{
    int lane = threadIdx.x & 63;
    int gw   = (blockIdx.x * blockDim.x + threadIdx.x) >> 6;
    int tw   = (gridDim.x * blockDim.x) >> 6;

    float wd[19], wb[19];
#pragma unroll
    for (int d = 0; d < 19; ++d) {
        float a = W1[d * HDIM + lane];
        float b = W1[(d + 19) * HDIM + lane];
        wd[d] = a - b;
        wb[d] = b;
    }
    float bb = b1[lane];

    for (int n = gw; n < N; n += tw) {
        float su = 0.f, sv = 0.f;
#pragma unroll
        for (int d4 = 0; d4 < 4; ++d4) {
            fv4 h4 = *(const fv4*)&x[(size_t)n * 16 + 4 * d4];
#pragma unroll
            for (int k = 0; k < 4; ++k) {
                su += h4[k] * wd[4 * d4 + k];
                sv += h4[k] * wb[4 * d4 + k];
            }
        }
#pragma unroll
        for (int d = 0; d < 3; ++d) {
            float h = pos[(size_t)n * 3 + d];
            su += h * wd[16 + d];
            sv += h * wb[16 + d];
        }
        U[(size_t)n * HDIM + lane] = f16r(su + bb);
        V[(size_t)n * HDIM + lane] = f16r(sv);
    }
}

// ---------------------------------------------------------------------------
// pre_mfma (conv2 layer-1): [N x 64] @ [64 x 128] on MFMA (fp16). Per wave:
// 16-node tile = 2 A-frag global loads + 32 MFMAs (hi+lo). B (Wpre hi/lo) in
// 128 VGPRs, loaded once per wave. C layout: col=lane&15 = out-channel,
// row=quad*4+r = node.
// ---------------------------------------------------------------------------
__global__ __launch_bounds__(256, 2) void pre_mfma_kernel(
    const unsigned short* __restrict__ h,     // fp16 N x 64
    const unsigned short* __restrict__ Whi,   // fp16 [c' 0..127][d 0..63]
    const unsigned short* __restrict__ Wlo,
    const float* __restrict__ b1,
    unsigned short* __restrict__ U, unsigned short* __restrict__ V, int nTiles)
{
    int lane = threadIdx.x & 63;
    int quad = lane >> 4;
    int m    = lane & 15;
    int gw   = (blockIdx.x * blockDim.x + threadIdx.x) >> 6;
    int tw   = (gridDim.x * blockDim.x) >> 6;

    hf8 Bh[8][2], Bl[8][2];
#pragma unroll
    for (int nt = 0; nt < 8; ++nt)
#pragma unroll
        for (int ks = 0; ks < 2; ++ks) {
            int off = (nt * 16 + m) * 64 + ks * 32 + quad * 8;
            Bh[nt][ks] = *(const hf8*)&Whi[off];
            Bl[nt][ks] = *(const hf8*)&Wlo[off];
        }
    float bias[4];
#pragma unroll
    for (int nt = 0; nt < 4; ++nt) bias[nt] = b1[nt * 16 + m];

    for (int t = gw; t < nTiles; t += tw) {
        int base = t * 16;
        hf8 A[2];
#pragma unroll
        for (int ks = 0; ks < 2; ++ks)
            A[ks] = *(const hf8*)&h[(size_t)(base + m) * HDIM + ks * 32 + quad * 8];

        f32x4 acc[8] = {{0,0,0,0},{0,0,0,0},{0,0,0,0},{0,0,0,0},
                        {0,0,0,0},{0,0,0,0},{0,0,0,0},{0,0,0,0}};
#pragma unroll
        for (int ks = 0; ks < 2; ++ks)
#pragma unroll
            for (int nt = 0; nt < 8; ++nt) {
                acc[nt] = __builtin_amdgcn_mfma_f32_16x16x32_f16(A[ks], Bl[nt][ks], acc[nt], 0, 0, 0);
                acc[nt] = __builtin_amdgcn_mfma_f32_16x16x32_f16(A[ks], Bh[nt][ks], acc[nt], 0, 0, 0);
            }

#pragma unroll
        for (int nt = 0; nt < 8; ++nt) {
            float bv = (nt < 4) ? bias[nt] : 0.f;
            unsigned short* __restrict__ dst = (nt < 4) ? U : V;
            int cc = (nt & 3) * 16 + m;
#pragma unroll
            for (int r = 0; r < 4; ++r) {
                int node = base + quad * 4 + r;
                dst[(size_t)node * HDIM + cc] = f16r(acc[nt][r] + bv);
            }
        }
    }
}

// ---------------------------------------------------------------------------
// edge_mfma: out[t][c] = relu( max_{16 edges} ( relu(u[t]+v[src]) @ W2 )[c] + b2[c] )
// Persistent software-pipelined version. Wave owns tiles of 4 nodes (64
// edges), grid-strided. Per tile:
//   1. fold previous-issued uB/vB -> fp16 A-frags (pk_add/pk_max, frees regs)
//   2. issue ALL next-tile loads (8 U rows + 8 V gathers + next src) --
//      ordering matters: in-order vmcnt means consumers must never sit
//      behind a newer slow gather, so consume-all-then-issue-all.
//   3. MFMA (f16) + max-reduce + store current tile.
// Steady state: 16 loads in flight per wave, no dispatch churn, zero LDS.
// ---------------------------------------------------------------------------
__global__ __launch_bounds__(256, 3) void edge_mfma_kernel(
    const unsigned short* __restrict__ U, const unsigned short* __restrict__ V,
    const int* __restrict__ src,
    const unsigned short* __restrict__ Whi, const unsigned short* __restrict__ Wlo,
    const float* __restrict__ b2, unsigned short* __restrict__ out, int NT)
{
    int tid  = threadIdx.x;
    int wave = tid >> 6;
    int lane = tid & 63;
    int quad = lane >> 4;
    int m    = lane & 15;

    hf8 Bh[4][2], Bl[4][2];
#pragma unroll
    for (int nt = 0; nt < 4; ++nt)
#pragma unroll
        for (int ks = 0; ks < 2; ++ks) {
            int off = (nt * 16 + m) * 64 + ks * 32 + quad * 8;
            Bh[nt][ks] = *(const hf8*)&Whi[off];
            Bl[nt][ks] = *(const hf8*)&Wlo[off];
        }
    float b2v = b2[lane];

    int t = blockIdx.x * 4 + wave;
    if (t >= NT) return;
    int stride = gridDim.x * 4;

    u32x4 uB[4][2], vB[4][2];

    // prologue: U rows then V gathers for first tile
    int s0 = src[(size_t)t * 64 + lane];
#pragma unroll
    for (int mt = 0; mt < 4; ++mt) {
        const u32x4* up = (const u32x4*)(U + (size_t)(t * 4 + mt) * HDIM + quad * 8);
        uB[mt][0] = up[0]; uB[mt][1] = up[4];
    }
#pragma unroll
    for (int mt = 0; mt < 4; ++mt) {
        int s_ = __shfl(s0, mt * 16 + m);
        const u32x4* vp = (const u32x4*)(V + (size_t)s_ * HDIM + quad * 8);
        vB[mt][0] = vp[0]; vB[mt][1] = vp[4];
    }
    int t1 = t + stride;
    int s1 = (t1 < NT) ? src[(size_t)t1 * 64 + lane] : 0;

    for (;;) {
        // 1. fold u+v -> relu -> fp16 A-frags (consumes uB/vB)
        u32x4 a[4][2];
#pragma unroll
        for (int mt = 0; mt < 4; ++mt)
#pragma unroll
            for (int hh = 0; hh < 2; ++hh)
#pragma unroll
                for (int p = 0; p < 4; ++p)
                    a[mt][hh][p] = addrelu2(uB[mt][hh][p], vB[mt][hh][p]);

        // 2. issue next tile's loads into uB/vB (+ src one tile further)
        int t2 = t1 + stride;
        int s2 = 0;
        if (t1 < NT) {
            s2 = (t2 < NT) ? src[(size_t)t2 * 64 + lane] : 0;
#pragma unroll
            for (int mt = 0; mt < 4; ++mt) {
                const u32x4* up = (const u32x4*)(U + (size_t)(t1 * 4 + mt) * HDIM + quad * 8);
                uB[mt][0] = up[0]; uB[mt][1] = up[4];
            }
#pragma unroll
            for (int mt = 0; mt < 4; ++mt) {
                int s_ = __shfl(s1, mt * 16 + m);
                const u32x4* vp = (const u32x4*)(V + (size_t)s_ * HDIM + quad * 8);
                vB[mt][0] = vp[0]; vB[mt][1] = vp[4];
            }
        }

        // 3. MFMA + max-reduce + store for current tile
#pragma unroll
        for (int mt = 0; mt < 4; ++mt) {
            hf8 A0 = __builtin_bit_cast(hf8, a[mt][0]);
            hf8 A1 = __builtin_bit_cast(hf8, a[mt][1]);
            f32x4 acc[4] = {{0,0,0,0},{0,0,0,0},{0,0,0,0},{0,0,0,0}};
#pragma unroll
            for (int nt = 0; nt < 4; ++nt) {
                acc[nt] = __builtin_amdgcn_mfma_f32_16x16x32_f16(A0, Bl[nt][0], acc[nt], 0, 0, 0);
                acc[nt] = __builtin_amdgcn_mfma_f32_16x16x32_f16(A0, Bh[nt][0], acc[nt], 0, 0, 0);
                acc[nt] = __builtin_amdgcn_mfma_f32_16x16x32_f16(A1, Bl[nt][1], acc[nt], 0, 0, 0);
                acc[nt] = __builtin_amdgcn_mfma_f32_16x16x32_f16(A1, Bh[nt][1], acc[nt], 0, 0, 0);
            }
            float mx[4];
#pragma unroll
            for (int nt = 0; nt < 4; ++nt)
                mx[nt] = fmaxf(fmaxf(acc[nt][0], acc[nt][1]), fmaxf(acc[nt][2], acc[nt][3]));
#pragma unroll
            for (int nt = 0; nt < 4; ++nt) {
                mx[nt] = fmaxf(mx[nt], __shfl_xor(mx[nt], 16));
                mx[nt] = fmaxf(mx[nt], __shfl_xor(mx[nt], 32));
            }
            float val = (quad == 0) ? mx[0] : (quad == 1) ? mx[1] : (quad == 2) ? mx[2] : mx[3];
            out[(size_t)(t * 4 + mt) * HDIM + lane] = f16r(fmaxf(val + b2v, 0.f));
        }

        if (t1 >= NT) break;
        t = t1; t1 = t2; s1 = s2;
    }
}

// ---------------------------------------------------------------------------
// region mean accumulation (fp16 input)
// ---------------------------------------------------------------------------
__global__ void region_mean_kernel(const unsigned short* __restrict__ h,
                                   const int* __restrict__ labels,
                                   float* __restrict__ qsums, int* __restrict__ qcnt, int N)
{
    __shared__ float ls[8 * 64];
    __shared__ int   lc[8];
    int tid  = threadIdx.x;
    int lane = tid & 63;
    int gw   = (blockIdx.x * blockDim.x + tid) >> 6;
    int tw   = (gridDim.x * blockDim.x) >> 6;

    float acc[8] = {0, 0, 0, 0, 0, 0, 0, 0};
    int   cnt[8] = {0, 0, 0, 0, 0, 0, 0, 0};

    for (int n = gw; n < N; n += tw) {
        int lbl = labels[n];
        float val = hs2f(h[(size_t)n * HDIM + lane]);
#pragma unroll
        for (int r = 0; r < 8; ++r) {
            acc[r] += (lbl == r) ? val : 0.f;
            cnt[r] += (lbl == r) ? 1 : 0;
        }
    }

    if (tid < 8) lc[tid] = 0;
    for (int idx = tid; idx < 512; idx += 256) ls[idx] = 0.f;
    __syncthreads();
#pragma unroll
    for (int r = 0; r < 8; ++r) atomicAdd(&ls[r * 64 + lane], acc[r]);
    if (lane == 0)
#pragma unroll
        for (int r = 0; r < 8; ++r) atomicAdd(&lc[r], cnt[r]);
    __syncthreads();
    for (int idx = tid; idx < 512; idx += 256) atomicAdd(&qsums[idx], ls[idx]);
    if (tid < 8) atomicAdd(&qcnt[tid], lc[tid]);
}

// ---------------------------------------------------------------------------
// tail: fully parallel quotient convs (8 nodes, 32 edges) + pool + linear.
// ---------------------------------------------------------------------------
#define EQ_MAX 64
__global__ void tail_kernel(const float* __restrict__ qsums, const int* __restrict__ qcnt,
                            const int* __restrict__ qei, int Eq,
                            const float* __restrict__ W31, const float* __restrict__ b31,
                            const float* __restrict__ W32, const float* __restrict__ b32,
                            const float* __restrict__ W41, const float* __restrict__ b41,
                            const float* __restrict__ W42, const float* __restrict__ b42,
                            const float* __restrict__ linW, const float* __restrict__ linb,
                            float* __restrict__ out)
{
    __shared__ float qx[512], uu[512], vv[512];
    __shared__ float hr[EQ_MAX * 64], me[EQ_MAX * 64];
    __shared__ __align__(16) float W2s[64 * 64];
    __shared__ int   qes[EQ_MAX], qet[EQ_MAX];
    __shared__ float emb[64];

    int tid = threadIdx.x;
    if (Eq > EQ_MAX) Eq = EQ_MAX;

    if (tid < Eq) { qes[tid] = qei[tid]; qet[tid] = qei[Eq + tid]; }
    for (int idx = tid; idx < 512; idx += 256) {
        int r = idx >> 6;
        int cc = qcnt[r];
        qx[idx] = (cc > 0) ? qsums[idx] / (float)cc : 0.f;
    }
    __syncthreads();

    for (int layer = 0; layer < 2; ++layer) {
        const float* W1p = layer ? W41 : W31;
        const float* b1p = layer ? b41 : b31;
        const float* W2p = layer ? W42 : W32;
        const float* b2p = layer ? b42 : b32;

        for (int idx = tid * 4; idx < 4096; idx += 1024)
            *(fv4*)&W2s[idx] = *(const fv4*)&W2p[idx];

        for (int idx = tid; idx < 512; idx += 256) {
            int t = idx >> 6, c = idx & 63;
            float su = 0.f, sv = 0.f;
#pragma unroll 8
            for (int d = 0; d < 64; ++d) {
                float hv = qx[t * 64 + d];
                float a = W1p[d * 64 + c];
                float b = W1p[(d + 64) * 64 + c];
                su += hv * (a - b);
                sv += hv * b;
            }
            uu[idx] = su + b1p[c];
            vv[idx] = sv;
        }
        __syncthreads();

        for (int idx = tid; idx < Eq * 64; idx += 256) {
            int e = idx >> 6, c = idx & 63;
            hr[idx] = fmaxf(uu[qet[e] * 64 + c] + vv[qes[e] * 64 + c], 0.f);
        }
        __syncthreads();

        {
            int c = tid & 63, e0 = tid >> 6;
            for (int e = e0; e < Eq; e += 4) {
                float acc = 0.f;
#pragma unroll 8
                for (int j = 0; j < 64; ++j)
                    acc += hr[e * 64 + j] * W2s[j * 64 + c];
                me[e * 64 + c] = acc;
            }
        }
        __syncthreads();

        for (int idx = tid; idx < 512; idx += 256) {
            int t = idx >> 6, c = idx & 63;
            float a = -INFINITY;
            for (int e = 0; e < Eq; ++e)
                if (qet[e] == t) a = fmaxf(a, me[e * 64 + c]);
            float vout = (a == -INFINITY) ? 0.f : (a + b2p[c]);
            qx[idx] = fmaxf(vout, 0.f);
        }
        __syncthreads();
    }

    if (tid < 64) {
        float s = 0.f;
        for (int r = 0; r < 8; ++r) s += qx[r * 64 + tid];
        emb[tid] = s;
    }
    __syncthreads();
    if (tid < 8) {
        float o = linb[tid];
        for (int c = 0; c < 64; ++c) o += emb[c] * linW[c * 8 + tid];
        out[tid] = o;
    }
}

// ---------------------------------------------------------------------------
extern "C" void kernel_launch(void* const* d_in, const int* in_sizes, int n_in,
                              void* d_out, int out_size, void* d_ws, size_t ws_size,
                              hipStream_t stream)
{
    const float* x    = (const float*)d_in[0];
    const float* pos  = (const float*)d_in[1];
    const int*   ei   = (const int*)d_in[2];
    const int*   lbl  = (const int*)d_in[3];
    const int*   qei  = (const int*)d_in[4];
    const float* W11 = (const float*)d_in[5];
    const float* b11 = (const float*)d_in[6];
    const float* W12 = (const float*)d_in[7];
    const float* b12 = (const float*)d_in[8];
    const float* W21 = (const float*)d_in[9];
    const float* b21 = (const float*)d_in[10];
    const float* W22 = (const float*)d_in[11];
    const float* b22 = (const float*)d_in[12];
    const float* W31 = (const float*)d_in[13];
    const float* b31 = (const float*)d_in[14];
    const float* W32 = (const float*)d_in[15];
    const float* b32 = (const float*)d_in[16];
    const float* W41 = (const float*)d_in[17];
    const float* b41 = (const float*)d_in[18];
    const float* W42 = (const float*)d_in[19];
    const float* b42 = (const float*)d_in[20];
    const float* linW = (const float*)d_in[21];
    const float* linb = (const float*)d_in[22];

    int N  = in_sizes[0] / 16;          // 100000
    int Eq = in_sizes[4] / 2;           // 32
    const int* src = ei;                // row 0 = src; tgt = repeat(arange(N),16)

    size_t NH = (size_t)N * HDIM;
    unsigned short* hbf = (unsigned short*)d_ws;   // fp16 N*64 (h1, then h2)
    unsigned short* Ub  = hbf + NH;                // fp16 N*64
    unsigned short* Vb  = Ub + NH;                 // fp16 N*64
    unsigned short* w2h1 = Vb + NH;
    unsigned short* w2l1 = w2h1 + 4096;
    unsigned short* w2h2 = w2l1 + 4096;
    unsigned short* w2l2 = w2h2 + 4096;
    unsigned short* wph  = w2l2 + 4096;            // 8192
    unsigned short* wpl  = wph + 8192;             // 8192
    float* qsums = (float*)(wpl + 8192);
    int*   qcnt  = (int*)(qsums + 512);

    (void)hipMemsetAsync(qsums, 0, 512 * sizeof(float) + 8 * sizeof(int), stream);

    int nTiles   = N / 16;              // pre_mfma tiles (16 nodes)
    int edgeNT   = N / 4;               // edge tiles (4 nodes per wave)

    prep_kernel<<<32, 256, 0, stream>>>(W12, W22, W21, w2h1, w2l1, w2h2, w2l2, wph, wpl);
    // conv1
    pre1_kernel<<<2048, 256, 0, stream>>>(x, pos, W11, b11, Ub, Vb, N);
    edge_mfma_kernel<<<1024, 256, 0, stream>>>(Ub, Vb, src, w2h1, w2l1, b12, hbf, edgeNT);
    // conv2
    pre_mfma_kernel<<<512, 256, 0, stream>>>(hbf, wph, wpl, b21, Ub, Vb, nTiles);
    edge_mfma_kernel<<<1024, 256, 0, stream>>>(Ub, Vb, src, w2h2, w2l2, b22, hbf, edgeNT);
    // quotient pooling + tail
    region_mean_kernel<<<1024, 256, 0, stream>>>(hbf, lbl, qsums, qcnt, N);
    tail_kernel<<<1, 256, 0, stream>>>(qsums, qcnt, qei, Eq,
                                       W31, b31, W32, b32,
                                       W41, b41, W42, b42,
                                       linW, linb, (float*)d_out);
}

// Round 5
// 382.657 us; speedup vs baseline: 1.1868x; 1.1868x over previous
//
#include <hip/hip_runtime.h>
#include <hip/hip_fp16.h>

typedef float fv4 __attribute__((ext_vector_type(4)));
using hf8   = __attribute__((ext_vector_type(8))) _Float16;  // 8 fp16 = 4 VGPRs (MFMA A/B frag)
using f32x4 = __attribute__((ext_vector_type(4))) float;     // MFMA C/D frag
using u32x4 = __attribute__((ext_vector_type(4))) unsigned;

#define HDIM 64

// fp32 -> fp16 bits (RNE)
__device__ __forceinline__ unsigned short f16r(float f) {
    return __half_as_ushort(__float2half(f));
}
__device__ __forceinline__ float hs2f(unsigned short s) {
    return __half2float(__ushort_as_half(s));
}
// packed fp16: relu(u+v) on 2 channels in one reg (v_pk_add_f16 + v_pk_max_f16)
__device__ __forceinline__ unsigned addrelu2(unsigned ua, unsigned va) {
    unsigned s, r;
    asm("v_pk_add_f16 %0, %1, %2" : "=v"(s) : "v"(ua), "v"(va));
    asm("v_pk_max_f16 %0, %1, 0" : "=v"(r) : "v"(s));
    return r;
}

// ---------------------------------------------------------------------------
// pre1 (+ fused prep + qsums zeroing): blocks < mainBlocks do
//   u = [x|pos] @ (W1a - W1b) + b1 ; v = [x|pos] @ W1b   (D = 19)
// blocks >= mainBlocks run the old prep_kernel body (weight split hi/lo)
// and zero qsums/qcnt. Removes two dispatches from the graph.
// ---------------------------------------------------------------------------
__global__ void pre1_kernel(
    const float* __restrict__ x, const float* __restrict__ pos,
    const float* __restrict__ W1, const float* __restrict__ b1,
    unsigned short* __restrict__ U, unsigned short* __restrict__ V, int N,
    int mainBlocks,
    const float* __restrict__ W2a, const float* __restrict__ W2b,
    const float* __restrict__ W1c,
    unsigned short* __restrict__ hiA, unsigned short* __restrict__ loA,
    unsigned short* __restrict__ hiB, unsigned short* __restrict__ loB,
    unsigned short* __restrict__ wph, unsigned short* __restrict__ wpl,
    int* __restrict__ qzero)
{
    if ((int)blockIdx.x >= mainBlocks) {
        int idx = (blockIdx.x - mainBlocks) * 256 + threadIdx.x;
        if (idx < 520) qzero[idx] = 0;                 // qsums[512] + qcnt[8]
        if (idx < 4096) {
            int j = idx >> 6, c = idx & 63;
            float w = W2a[idx];
            unsigned short h = f16r(w);
            unsigned short l = f16r(w - hs2f(h));
            hiA[c * 64 + j] = h; loA[c * 64 + j] = l;
            w = W2b[idx];
            h = f16r(w);
            l = f16r(w - hs2f(h));
            hiB[c * 64 + j] = h; loB[c * 64 + j] = l;
        }
        if (idx < 8192) {
            int d = idx & 63, cp = idx >> 6;
            float w = (cp < 64) ? (W1c[d * 64 + cp] - W1c[(d + 64) * 64 + cp])
                                : W1c[(d + 64) * 64 + (cp - 64)];
            unsigned short h = f16r(w);
            unsigned short l = f16r(w - hs2f(h));
            wph[cp * 64 + d] = h;
            wpl[cp * 64 + d] = l;
        }
        return;
    }

    int lane = threadIdx.x & 63;
    int gw   = (blockIdx.x * blockDim.x + threadIdx.x) >> 6;
    int tw   = (mainBlocks * blockDim.x) >> 6;

    float wd[19], wb[19];
#pragma unroll
    for (int d = 0; d < 19; ++d) {
        float a = W1[d * HDIM + lane];
        float b = W1[(d + 19) * HDIM + lane];
        wd[d] = a - b;
        wb[d] = b;
    }
    float bb = b1[lane];

    for (int n = gw; n < N; n += tw) {
        float su = 0.f, sv = 0.f;
#pragma unroll
        for (int d4 = 0; d4 < 4; ++d4) {
            fv4 h4 = *(const fv4*)&x[(size_t)n * 16 + 4 * d4];
#pragma unroll
            for (int k = 0; k < 4; ++k) {
                su += h4[k] * wd[4 * d4 + k];
                sv += h4[k] * wb[4 * d4 + k];
            }
        }
#pragma unroll
        for (int d = 0; d < 3; ++d) {
            float h = pos[(size_t)n * 3 + d];
            su += h * wd[16 + d];
            sv += h * wb[16 + d];
        }
        U[(size_t)n * HDIM + lane] = f16r(su + bb);
        V[(size_t)n * HDIM + lane] = f16r(sv);
    }
}

// ---------------------------------------------------------------------------
// pre_mfma (conv2 layer-1): [N x 64] @ [64 x 128] on MFMA (fp16). Per wave:
// 16-node tile = 2 A-frag global loads + 32 MFMAs (hi+lo). B (Wpre hi/lo) in
// 128 VGPRs, loaded once per wave. C layout: col=lane&15 = out-channel,
// row=quad*4+r = node.
// ---------------------------------------------------------------------------
__global__ __launch_bounds__(256, 2) void pre_mfma_kernel(
    const unsigned short* __restrict__ h,     // fp16 N x 64
    const unsigned short* __restrict__ Whi,   // fp16 [c' 0..127][d 0..63]
    const unsigned short* __restrict__ Wlo,
    const float* __restrict__ b1,
    unsigned short* __restrict__ U, unsigned short* __restrict__ V, int nTiles)
{
    int lane = threadIdx.x & 63;
    int quad = lane >> 4;
    int m    = lane & 15;
    int gw   = (blockIdx.x * blockDim.x + threadIdx.x) >> 6;
    int tw   = (gridDim.x * blockDim.x) >> 6;

    hf8 Bh[8][2], Bl[8][2];
#pragma unroll
    for (int nt = 0; nt < 8; ++nt)
#pragma unroll
        for (int ks = 0; ks < 2; ++ks) {
            int off = (nt * 16 + m) * 64 + ks * 32 + quad * 8;
            Bh[nt][ks] = *(const hf8*)&Whi[off];
            Bl[nt][ks] = *(const hf8*)&Wlo[off];
        }
    float bias[4];
#pragma unroll
    for (int nt = 0; nt < 4; ++nt) bias[nt] = b1[nt * 16 + m];

    for (int t = gw; t < nTiles; t += tw) {
        int base = t * 16;
        hf8 A[2];
#pragma unroll
        for (int ks = 0; ks < 2; ++ks)
            A[ks] = *(const hf8*)&h[(size_t)(base + m) * HDIM + ks * 32 + quad * 8];

        f32x4 acc[8] = {{0,0,0,0},{0,0,0,0},{0,0,0,0},{0,0,0,0},
                        {0,0,0,0},{0,0,0,0},{0,0,0,0},{0,0,0,0}};
#pragma unroll
        for (int ks = 0; ks < 2; ++ks)
#pragma unroll
            for (int nt = 0; nt < 8; ++nt) {
                acc[nt] = __builtin_amdgcn_mfma_f32_16x16x32_f16(A[ks], Bl[nt][ks], acc[nt], 0, 0, 0);
                acc[nt] = __builtin_amdgcn_mfma_f32_16x16x32_f16(A[ks], Bh[nt][ks], acc[nt], 0, 0, 0);
            }

#pragma unroll
        for (int nt = 0; nt < 8; ++nt) {
            float bv = (nt < 4) ? bias[nt] : 0.f;
            unsigned short* __restrict__ dst = (nt < 4) ? U : V;
            int cc = (nt & 3) * 16 + m;
#pragma unroll
            for (int r = 0; r < 4; ++r) {
                int node = base + quad * 4 + r;
                dst[(size_t)node * HDIM + cc] = f16r(acc[nt][r] + bv);
            }
        }
    }
}

// ---------------------------------------------------------------------------
// edge_mfma: out[t][c] = relu( max_{16 edges} ( relu(u[t]+v[src]) @ W2 )[c] + b2[c] )
// Depth-2 prefetch, block-ordered dispatch (3125 blocks x 32 nodes).
// Per wave: 8 nodes = 2 tiles. W2 hi/lo staged to LDS (XOR-swizzled,
// conflict-free) so B reads live in the lgkmcnt domain and stay off the
// in-order vmcnt path. Barrier sits BEFORE gather issue (syncthreads drains
// vmcnt(0)). Then: issue all 32 gathers (A,B) -> fold/compute tile A under a
// counted vmcnt (B's 16 loads still in flight) -> fold/compute tile B.
// ---------------------------------------------------------------------------
__global__ __launch_bounds__(256, 3) void edge_mfma_kernel(
    const unsigned short* __restrict__ U, const unsigned short* __restrict__ V,
    const int* __restrict__ src,
    const unsigned short* __restrict__ Whi, const unsigned short* __restrict__ Wlo,
    const float* __restrict__ b2, unsigned short* __restrict__ out)
{
    __shared__ __align__(16) unsigned short Wsh[8192];   // 16 KB: hi @0, lo @8192B

    int tid  = threadIdx.x;
    int wave = tid >> 6;
    int lane = tid & 63;
    int quad = lane >> 4;
    int m    = lane & 15;

    int nb = blockIdx.x * 32 + wave * 8;     // this wave's 8 nodes

    // ---- stage W2 hi/lo into LDS with row-XOR swizzle ------------------
    // chunk c: byte b = (c&511)*16 in region (c>>9); dest b^=((b>>7)&7)<<4
#pragma unroll
    for (int it = 0; it < 4; ++it) {
        int chunk = it * 256 + tid;
        int reg   = it >> 1;                  // it 0,1 -> hi ; 2,3 -> lo
        int b     = (chunk & 511) * 16;
        int bs    = b ^ (((b >> 7) & 7) << 4);
        const unsigned short* sp = reg ? Wlo : Whi;
        u32x4 d = *(const u32x4*)((const char*)sp + b);
        *(u32x4*)((char*)Wsh + reg * 8192 + bs) = d;
    }

    int  srcA = src[(size_t)nb * 16 + lane];
    int  srcB = src[(size_t)(nb + 4) * 16 + lane];
    float b2v = b2[lane];

    __syncthreads();     // drains everything; placed BEFORE gather issue

    // ---- issue all gathers: tile A then tile B -------------------------
    u32x4 uA[4][2], vA[4][2], uB[4][2], vB[4][2];
#pragma unroll
    for (int mt = 0; mt < 4; ++mt) {
        const u32x4* up = (const u32x4*)(U + (size_t)(nb + mt) * HDIM + quad * 8);
        uA[mt][0] = up[0]; uA[mt][1] = up[4];
    }
#pragma unroll
    for (int mt = 0; mt < 4; ++mt) {
        int s_ = __shfl(srcA, mt * 16 + m);
        const u32x4* vp = (const u32x4*)(V + (size_t)s_ * HDIM + quad * 8);
        vA[mt][0] = vp[0]; vA[mt][1] = vp[4];
    }
#pragma unroll
    for (int mt = 0; mt < 4; ++mt) {
        const u32x4* up = (const u32x4*)(U + (size_t)(nb + 4 + mt) * HDIM + quad * 8);
        uB[mt][0] = up[0]; uB[mt][1] = up[4];
    }
#pragma unroll
    for (int mt = 0; mt < 4; ++mt) {
        int s_ = __shfl(srcB, mt * 16 + m);
        const u32x4* vp = (const u32x4*)(V + (size_t)s_ * HDIM + quad * 8);
        vB[mt][0] = vp[0]; vB[mt][1] = vp[4];
    }

    // ---- B fragments from LDS (lgkmcnt domain, overlaps gathers) -------
    hf8 Bh[4][2], Bl[4][2];
#pragma unroll
    for (int nt = 0; nt < 4; ++nt)
#pragma unroll
        for (int ks = 0; ks < 2; ++ks) {
            int b  = nt * 2048 + m * 128 + ks * 64 + quad * 16;
            int bs = b ^ ((m & 7) << 4);
            Bh[nt][ks] = *(const hf8*)((const char*)Wsh + bs);
            Bl[nt][ks] = *(const hf8*)((const char*)Wsh + 8192 + bs);
        }

    // ---- tile A (B's 16 gathers remain in flight) ----------------------
#pragma unroll
    for (int half = 0; half < 2; ++half) {
        u32x4 (*uP)[2] = half ? uB : uA;
        u32x4 (*vP)[2] = half ? vB : vA;
        int rowBase = nb + half * 4;

#pragma unroll
        for (int mt = 0; mt < 4; ++mt) {
            u32x4 a0, a1;
#pragma unroll
            for (int p = 0; p < 4; ++p) {
                a0[p] = addrelu2(uP[mt][0][p], vP[mt][0][p]);
                a1[p] = addrelu2(uP[mt][1][p], vP[mt][1][p]);
            }
            hf8 A0 = __builtin_bit_cast(hf8, a0);
            hf8 A1 = __builtin_bit_cast(hf8, a1);
            f32x4 acc[4] = {{0,0,0,0},{0,0,0,0},{0,0,0,0},{0,0,0,0}};
#pragma unroll
            for (int nt = 0; nt < 4; ++nt) {
                acc[nt] = __builtin_amdgcn_mfma_f32_16x16x32_f16(A0, Bl[nt][0], acc[nt], 0, 0, 0);
                acc[nt] = __builtin_amdgcn_mfma_f32_16x16x32_f16(A0, Bh[nt][0], acc[nt], 0, 0, 0);
                acc[nt] = __builtin_amdgcn_mfma_f32_16x16x32_f16(A1, Bl[nt][1], acc[nt], 0, 0, 0);
                acc[nt] = __builtin_amdgcn_mfma_f32_16x16x32_f16(A1, Bh[nt][1], acc[nt], 0, 0, 0);
            }
            float mx[4];
#pragma unroll
            for (int nt = 0; nt < 4; ++nt)
                mx[nt] = fmaxf(fmaxf(acc[nt][0], acc[nt][1]), fmaxf(acc[nt][2], acc[nt][3]));
#pragma unroll
            for (int nt = 0; nt < 4; ++nt) {
                mx[nt] = fmaxf(mx[nt], __shfl_xor(mx[nt], 16));
                mx[nt] = fmaxf(mx[nt], __shfl_xor(mx[nt], 32));
            }
            float val = (quad == 0) ? mx[0] : (quad == 1) ? mx[1] : (quad == 2) ? mx[2] : mx[3];
            out[(size_t)(rowBase + mt) * HDIM + lane] = f16r(fmaxf(val + b2v, 0.f));
        }
    }
}

// ---------------------------------------------------------------------------
// region mean accumulation (fp16 input)
// ---------------------------------------------------------------------------
__global__ void region_mean_kernel(const unsigned short* __restrict__ h,
                                   const int* __restrict__ labels,
                                   float* __restrict__ qsums, int* __restrict__ qcnt, int N)
{
    __shared__ float ls[8 * 64];
    __shared__ int   lc[8];
    int tid  = threadIdx.x;
    int lane = tid & 63;
    int gw   = (blockIdx.x * blockDim.x + tid) >> 6;
    int tw   = (gridDim.x * blockDim.x) >> 6;

    float acc[8] = {0, 0, 0, 0, 0, 0, 0, 0};
    int   cnt[8] = {0, 0, 0, 0, 0, 0, 0, 0};

    for (int n = gw; n < N; n += tw) {
        int lbl = labels[n];
        float val = hs2f(h[(size_t)n * HDIM + lane]);
#pragma unroll
        for (int r = 0; r < 8; ++r) {
            acc[r] += (lbl == r) ? val : 0.f;
            cnt[r] += (lbl == r) ? 1 : 0;
        }
    }

    if (tid < 8) lc[tid] = 0;
    for (int idx = tid; idx < 512; idx += 256) ls[idx] = 0.f;
    __syncthreads();
#pragma unroll
    for (int r = 0; r < 8; ++r) atomicAdd(&ls[r * 64 + lane], acc[r]);
    if (lane == 0)
#pragma unroll
        for (int r = 0; r < 8; ++r) atomicAdd(&lc[r], cnt[r]);
    __syncthreads();
    for (int idx = tid; idx < 512; idx += 256) atomicAdd(&qsums[idx], ls[idx]);
    if (tid < 8) atomicAdd(&qcnt[tid], lc[tid]);
}

// ---------------------------------------------------------------------------
// tail: fully parallel quotient convs (8 nodes, 32 edges) + pool + linear.
// ---------------------------------------------------------------------------
#define EQ_MAX 64
__global__ void tail_kernel(const float* __restrict__ qsums, const int* __restrict__ qcnt,
                            const int* __restrict__ qei, int Eq,
                            const float* __restrict__ W31, const float* __restrict__ b31,
                            const float* __restrict__ W32, const float* __restrict__ b32,
                            const float* __restrict__ W41, const float* __restrict__ b41,
                            const float* __restrict__ W42, const float* __restrict__ b42,
                            const float* __restrict__ linW, const float* __restrict__ linb,
                            float* __restrict__ out)
{
    __shared__ float qx[512], uu[512], vv[512];
    __shared__ float hr[EQ_MAX * 64], me[EQ_MAX * 64];
    __shared__ __align__(16) float W2s[64 * 64];
    __shared__ int   qes[EQ_MAX], qet[EQ_MAX];
    __shared__ float emb[64];

    int tid = threadIdx.x;
    if (Eq > EQ_MAX) Eq = EQ_MAX;

    if (tid < Eq) { qes[tid] = qei[tid]; qet[tid] = qei[Eq + tid]; }
    for (int idx = tid; idx < 512; idx += 256) {
        int r = idx >> 6;
        int cc = qcnt[r];
        qx[idx] = (cc > 0) ? qsums[idx] / (float)cc : 0.f;
    }
    __syncthreads();

    for (int layer = 0; layer < 2; ++layer) {
        const float* W1p = layer ? W41 : W31;
        const float* b1p = layer ? b41 : b31;
        const float* W2p = layer ? W42 : W32;
        const float* b2p = layer ? b42 : b32;

        for (int idx = tid * 4; idx < 4096; idx += 1024)
            *(fv4*)&W2s[idx] = *(const fv4*)&W2p[idx];

        for (int idx = tid; idx < 512; idx += 256) {
            int t = idx >> 6, c = idx & 63;
            float su = 0.f, sv = 0.f;
#pragma unroll 8
            for (int d = 0; d < 64; ++d) {
                float hv = qx[t * 64 + d];
                float a = W1p[d * 64 + c];
                float b = W1p[(d + 64) * 64 + c];
                su += hv * (a - b);
                sv += hv * b;
            }
            uu[idx] = su + b1p[c];
            vv[idx] = sv;
        }
        __syncthreads();

        for (int idx = tid; idx < Eq * 64; idx += 256) {
            int e = idx >> 6, c = idx & 63;
            hr[idx] = fmaxf(uu[qet[e] * 64 + c] + vv[qes[e] * 64 + c], 0.f);
        }
        __syncthreads();

        {
            int c = tid & 63, e0 = tid >> 6;
            for (int e = e0; e < Eq; e += 4) {
                float acc = 0.f;
#pragma unroll 8
                for (int j = 0; j < 64; ++j)
                    acc += hr[e * 64 + j] * W2s[j * 64 + c];
                me[e * 64 + c] = acc;
            }
        }
        __syncthreads();

        for (int idx = tid; idx < 512; idx += 256) {
            int t = idx >> 6, c = idx & 63;
            float a = -INFINITY;
            for (int e = 0; e < Eq; ++e)
                if (qet[e] == t) a = fmaxf(a, me[e * 64 + c]);
            float vout = (a == -INFINITY) ? 0.f : (a + b2p[c]);
            qx[idx] = fmaxf(vout, 0.f);
        }
        __syncthreads();
    }

    if (tid < 64) {
        float s = 0.f;
        for (int r = 0; r < 8; ++r) s += qx[r * 64 + tid];
        emb[tid] = s;
    }
    __syncthreads();
    if (tid < 8) {
        float o = linb[tid];
        for (int c = 0; c < 64; ++c) o += emb[c] * linW[c * 8 + tid];
        out[tid] = o;
    }
}

// ---------------------------------------------------------------------------
extern "C" void kernel_launch(void* const* d_in, const int* in_sizes, int n_in,
                              void* d_out, int out_size, void* d_ws, size_t ws_size,
                              hipStream_t stream)
{
    const float* x    = (const float*)d_in[0];
    const float* pos  = (const float*)d_in[1];
    const int*   ei   = (const int*)d_in[2];
    const int*   lbl  = (const int*)d_in[3];
    const int*   qei  = (const int*)d_in[4];
    const float* W11 = (const float*)d_in[5];
    const float* b11 = (const float*)d_in[6];
    const float* W12 = (const float*)d_in[7];
    const float* b12 = (const float*)d_in[8];
    const float* W21 = (const float*)d_in[9];
    const float* b21 = (const float*)d_in[10];
    const float* W22 = (const float*)d_in[11];
    const float* b22 = (const float*)d_in[12];
    const float* W31 = (const float*)d_in[13];
    const float* b31 = (const float*)d_in[14];
    const float* W32 = (const float*)d_in[15];
    const float* b32 = (const float*)d_in[16];
    const float* W41 = (const float*)d_in[17];
    const float* b41 = (const float*)d_in[18];
    const float* W42 = (const float*)d_in[19];
    const float* b42 = (const float*)d_in[20];
    const float* linW = (const float*)d_in[21];
    const float* linb = (const float*)d_in[22];

    int N  = in_sizes[0] / 16;          // 100000
    int Eq = in_sizes[4] / 2;           // 32
    const int* src = ei;                // row 0 = src; tgt = repeat(arange(N),16)

    size_t NH = (size_t)N * HDIM;
    unsigned short* hbf = (unsigned short*)d_ws;   // fp16 N*64 (h1, then h2)
    unsigned short* Ub  = hbf + NH;                // fp16 N*64
    unsigned short* Vb  = Ub + NH;                 // fp16 N*64
    unsigned short* w2h1 = Vb + NH;
    unsigned short* w2l1 = w2h1 + 4096;
    unsigned short* w2h2 = w2l1 + 4096;
    unsigned short* w2l2 = w2h2 + 4096;
    unsigned short* wph  = w2l2 + 4096;            // 8192
    unsigned short* wpl  = wph + 8192;             // 8192
    float* qsums = (float*)(wpl + 8192);
    int*   qcnt  = (int*)(qsums + 512);

    int nTiles      = N / 16;           // pre_mfma tiles (6250)
    int edgeBlocks  = N / 32;           // edge blocks, 32 nodes each (3125)
    int mainBlocks  = 2048;

    // conv1 (pre1 + fused prep + qsums zeroing)
    pre1_kernel<<<mainBlocks + 32, 256, 0, stream>>>(
        x, pos, W11, b11, Ub, Vb, N, mainBlocks,
        W12, W22, W21, w2h1, w2l1, w2h2, w2l2, wph, wpl, (int*)qsums);
    edge_mfma_kernel<<<edgeBlocks, 256, 0, stream>>>(Ub, Vb, src, w2h1, w2l1, b12, hbf);
    // conv2
    pre_mfma_kernel<<<512, 256, 0, stream>>>(hbf, wph, wpl, b21, Ub, Vb, nTiles);
    edge_mfma_kernel<<<edgeBlocks, 256, 0, stream>>>(Ub, Vb, src, w2h2, w2l2, b22, hbf);
    // quotient pooling + tail
    region_mean_kernel<<<1024, 256, 0, stream>>>(hbf, lbl, qsums, qcnt, N);
    tail_kernel<<<1, 256, 0, stream>>>(qsums, qcnt, qei, Eq,
                                       W31, b31, W32, b32,
                                       W41, b41, W42, b42,
                                       linW, linb, (float*)d_out);
}

// Round 6
// 287.299 us; speedup vs baseline: 1.5808x; 1.3319x over previous
//
#include <hip/hip_runtime.h>
#include <hip/hip_fp16.h>

typedef float fv4 __attribute__((ext_vector_type(4)));
using hf8   = __attribute__((ext_vector_type(8))) _Float16;  // 8 fp16 = 4 VGPRs (MFMA A/B frag)
using f32x4 = __attribute__((ext_vector_type(4))) float;     // MFMA C/D frag
using u32x4 = __attribute__((ext_vector_type(4))) unsigned;

#define HDIM 64

// fp32 -> fp16 bits (RNE)
__device__ __forceinline__ unsigned short f16r(float f) {
    return __half_as_ushort(__float2half(f));
}
__device__ __forceinline__ float hs2f(unsigned short s) {
    return __half2float(__ushort_as_half(s));
}
// packed fp16: relu(u+v) on 2 channels in one reg (v_pk_add_f16 + v_pk_max_f16)
__device__ __forceinline__ unsigned addrelu2(unsigned ua, unsigned va) {
    unsigned s, r;
    asm("v_pk_add_f16 %0, %1, %2" : "=v"(s) : "v"(ua), "v"(va));
    asm("v_pk_max_f16 %0, %1, 0" : "=v"(r) : "v"(s));
    return r;
}

// ---------------------------------------------------------------------------
// pre1 (+ fused prep + qsums zeroing): blocks < mainBlocks do
//   u = [x|pos] @ (W1a - W1b) + b1 ; v = [x|pos] @ W1b   (D = 19)
// blocks >= mainBlocks run the prep body (weight split hi/lo) and zero qsums.
// ---------------------------------------------------------------------------
__global__ void pre1_kernel(
    const float* __restrict__ x, const float* __restrict__ pos,
    const float* __restrict__ W1, const float* __restrict__ b1,
    unsigned short* __restrict__ U, unsigned short* __restrict__ V, int N,
    int mainBlocks,
    const float* __restrict__ W2a, const float* __restrict__ W2b,
    const float* __restrict__ W1c,
    unsigned short* __restrict__ hiA, unsigned short* __restrict__ loA,
    unsigned short* __restrict__ hiB, unsigned short* __restrict__ loB,
    unsigned short* __restrict__ wph, unsigned short* __restrict__ wpl,
    int* __restrict__ qzero)
{
    if ((int)blockIdx.x >= mainBlocks) {
        int idx = (blockIdx.x - mainBlocks) * 256 + threadIdx.x;
        if (idx < 520) qzero[idx] = 0;                 // qsums[512] + qcnt[8]
        if (idx < 4096) {
            int j = idx >> 6, c = idx & 63;
            float w = W2a[idx];
            unsigned short h = f16r(w);
            unsigned short l = f16r(w - hs2f(h));
            hiA[c * 64 + j] = h; loA[c * 64 + j] = l;
            w = W2b[idx];
            h = f16r(w);
            l = f16r(w - hs2f(h));
            hiB[c * 64 + j] = h; loB[c * 64 + j] = l;
        }
        if (idx < 8192) {
            int d = idx & 63, cp = idx >> 6;
            float w = (cp < 64) ? (W1c[d * 64 + cp] - W1c[(d + 64) * 64 + cp])
                                : W1c[(d + 64) * 64 + (cp - 64)];
            unsigned short h = f16r(w);
            unsigned short l = f16r(w - hs2f(h));
            wph[cp * 64 + d] = h;
            wpl[cp * 64 + d] = l;
        }
        return;
    }

    int lane = threadIdx.x & 63;
    int gw   = (blockIdx.x * blockDim.x + threadIdx.x) >> 6;
    int tw   = (mainBlocks * blockDim.x) >> 6;

    float wd[19], wb[19];
#pragma unroll
    for (int d = 0; d < 19; ++d) {
        float a = W1[d * HDIM + lane];
        float b = W1[(d + 19) * HDIM + lane];
        wd[d] = a - b;
        wb[d] = b;
    }
    float bb = b1[lane];

    for (int n = gw; n < N; n += tw) {
        float su = 0.f, sv = 0.f;
#pragma unroll
        for (int d4 = 0; d4 < 4; ++d4) {
            fv4 h4 = *(const fv4*)&x[(size_t)n * 16 + 4 * d4];
#pragma unroll
            for (int k = 0; k < 4; ++k) {
                su += h4[k] * wd[4 * d4 + k];
                sv += h4[k] * wb[4 * d4 + k];
            }
        }
#pragma unroll
        for (int d = 0; d < 3; ++d) {
            float h = pos[(size_t)n * 3 + d];
            su += h * wd[16 + d];
            sv += h * wb[16 + d];
        }
        U[(size_t)n * HDIM + lane] = f16r(su + bb);
        V[(size_t)n * HDIM + lane] = f16r(sv);
    }
}

// ---------------------------------------------------------------------------
// pre_mfma (conv2 layer-1): [N x 64] @ [64 x 128] on MFMA (fp16). Per wave:
// 16-node tile = 2 A-frag global loads + 32 MFMAs (hi+lo). B (Wpre hi/lo) in
// 128 VGPRs, loaded once per wave. C layout: col=lane&15 = out-channel,
// row=quad*4+r = node.
// ---------------------------------------------------------------------------
__global__ __launch_bounds__(256, 2) void pre_mfma_kernel(
    const unsigned short* __restrict__ h,     // fp16 N x 64
    const unsigned short* __restrict__ Whi,   // fp16 [c' 0..127][d 0..63]
    const unsigned short* __restrict__ Wlo,
    const float* __restrict__ b1,
    unsigned short* __restrict__ U, unsigned short* __restrict__ V, int nTiles)
{
    int lane = threadIdx.x & 63;
    int quad = lane >> 4;
    int m    = lane & 15;
    int gw   = (blockIdx.x * blockDim.x + threadIdx.x) >> 6;
    int tw   = (gridDim.x * blockDim.x) >> 6;

    hf8 Bh[8][2], Bl[8][2];
#pragma unroll
    for (int nt = 0; nt < 8; ++nt)
#pragma unroll
        for (int ks = 0; ks < 2; ++ks) {
            int off = (nt * 16 + m) * 64 + ks * 32 + quad * 8;
            Bh[nt][ks] = *(const hf8*)&Whi[off];
            Bl[nt][ks] = *(const hf8*)&Wlo[off];
        }
    float bias[4];
#pragma unroll
    for (int nt = 0; nt < 4; ++nt) bias[nt] = b1[nt * 16 + m];

    for (int t = gw; t < nTiles; t += tw) {
        int base = t * 16;
        hf8 A[2];
#pragma unroll
        for (int ks = 0; ks < 2; ++ks)
            A[ks] = *(const hf8*)&h[(size_t)(base + m) * HDIM + ks * 32 + quad * 8];

        f32x4 acc[8] = {{0,0,0,0},{0,0,0,0},{0,0,0,0},{0,0,0,0},
                        {0,0,0,0},{0,0,0,0},{0,0,0,0},{0,0,0,0}};
#pragma unroll
        for (int ks = 0; ks < 2; ++ks)
#pragma unroll
            for (int nt = 0; nt < 8; ++nt) {
                acc[nt] = __builtin_amdgcn_mfma_f32_16x16x32_f16(A[ks], Bl[nt][ks], acc[nt], 0, 0, 0);
                acc[nt] = __builtin_amdgcn_mfma_f32_16x16x32_f16(A[ks], Bh[nt][ks], acc[nt], 0, 0, 0);
            }

#pragma unroll
        for (int nt = 0; nt < 8; ++nt) {
            float bv = (nt < 4) ? bias[nt] : 0.f;
            unsigned short* __restrict__ dst = (nt < 4) ? U : V;
            int cc = (nt & 3) * 16 + m;
#pragma unroll
            for (int r = 0; r < 4; ++r) {
                int node = base + quad * 4 + r;
                dst[(size_t)node * HDIM + cc] = f16r(acc[nt][r] + bv);
            }
        }
    }
}

// ---------------------------------------------------------------------------
// edge_mfma: out[t][c] = relu( max_{16 edges} ( relu(u[t]+v[src]) @ W2 )[c] + b2[c] )
// Depth-2 prefetch, block-ordered (3125 blocks x 32 nodes), NO runtime-indexed
// register arrays (r5's scratch-spill bug: `half ? uB : uA` sent 128 regs to
// local memory -> 165MB scratch writes). Register diet:
//   - U rows: block's 32 contiguous rows staged once to LDS (4KB), read back
//     by broadcast ds_read at fold time (frees 64 VGPRs + kills dup gathers)
//   - B frags: read from swizzled LDS right before each MFMA (frees ~56 VGPRs)
//   - only the 16 V-gather dwordx4 stay resident (64 VGPRs, static names)
// Tile-A fold waits on counted vmcnt while tile-B's 8 gathers stay in flight.
// ---------------------------------------------------------------------------
#define FOLD_HALF(V0, V1, OFF)                                                     \
    _Pragma("unroll")                                                              \
    for (int mt = 0; mt < 4; ++mt) {                                               \
        int urow = wave * 8 + (OFF) + mt;                                          \
        u32x4 u0 = *(const u32x4*)((const char*)Ush + urow * 128 + quad * 16);     \
        u32x4 u1 = *(const u32x4*)((const char*)Ush + urow * 128 + 64 + quad * 16);\
        u32x4 a0, a1;                                                              \
        _Pragma("unroll")                                                          \
        for (int p = 0; p < 4; ++p) {                                              \
            a0[p] = addrelu2(u0[p], V0[mt][p]);                                    \
            a1[p] = addrelu2(u1[p], V1[mt][p]);                                    \
        }                                                                          \
        hf8 A0 = __builtin_bit_cast(hf8, a0);                                      \
        hf8 A1 = __builtin_bit_cast(hf8, a1);                                      \
        f32x4 acc[4] = {{0,0,0,0},{0,0,0,0},{0,0,0,0},{0,0,0,0}};                  \
        _Pragma("unroll")                                                          \
        for (int nt = 0; nt < 4; ++nt) {                                           \
            int bb  = nt * 2048 + m * 128 + quad * 16;                             \
            int bs0 = bb ^ ((m & 7) << 4);                                         \
            int bs1 = (bb + 64) ^ ((m & 7) << 4);                                  \
            hf8 Bh0 = *(const hf8*)((const char*)Wsh + bs0);                       \
            hf8 Bl0 = *(const hf8*)((const char*)Wsh + 8192 + bs0);                \
            hf8 Bh1 = *(const hf8*)((const char*)Wsh + bs1);                       \
            hf8 Bl1 = *(const hf8*)((const char*)Wsh + 8192 + bs1);                \
            acc[nt] = __builtin_amdgcn_mfma_f32_16x16x32_f16(A0, Bl0, acc[nt], 0, 0, 0); \
            acc[nt] = __builtin_amdgcn_mfma_f32_16x16x32_f16(A0, Bh0, acc[nt], 0, 0, 0); \
            acc[nt] = __builtin_amdgcn_mfma_f32_16x16x32_f16(A1, Bl1, acc[nt], 0, 0, 0); \
            acc[nt] = __builtin_amdgcn_mfma_f32_16x16x32_f16(A1, Bh1, acc[nt], 0, 0, 0); \
        }                                                                          \
        float mx[4];                                                               \
        _Pragma("unroll")                                                          \
        for (int nt = 0; nt < 4; ++nt)                                             \
            mx[nt] = fmaxf(fmaxf(acc[nt][0], acc[nt][1]), fmaxf(acc[nt][2], acc[nt][3])); \
        _Pragma("unroll")                                                          \
        for (int nt = 0; nt < 4; ++nt) {                                           \
            mx[nt] = fmaxf(mx[nt], __shfl_xor(mx[nt], 16));                        \
            mx[nt] = fmaxf(mx[nt], __shfl_xor(mx[nt], 32));                        \
        }                                                                          \
        float val = (quad == 0) ? mx[0] : (quad == 1) ? mx[1] : (quad == 2) ? mx[2] : mx[3]; \
        out[(size_t)(nb + (OFF) + mt) * HDIM + lane] = f16r(fmaxf(val + b2v, 0.f));\
    }

__global__ __launch_bounds__(256, 3) void edge_mfma_kernel(
    const unsigned short* __restrict__ U, const unsigned short* __restrict__ V,
    const int* __restrict__ src,
    const unsigned short* __restrict__ Whi, const unsigned short* __restrict__ Wlo,
    const float* __restrict__ b2, unsigned short* __restrict__ out)
{
    __shared__ __align__(16) unsigned short Wsh[8192];   // 16 KB: hi @0, lo @8192B
    __shared__ __align__(16) unsigned short Ush[2048];   // 4 KB: 32 U rows

    int tid  = threadIdx.x;
    int wave = tid >> 6;
    int lane = tid & 63;
    int quad = lane >> 4;
    int m    = lane & 15;

    int nbB = blockIdx.x * 32;           // block node base
    int nb  = nbB + wave * 8;            // wave's 8 nodes

    // ---- stage W2 hi/lo into LDS with row-XOR swizzle ------------------
#pragma unroll
    for (int it = 0; it < 4; ++it) {
        int chunk = it * 256 + tid;
        int reg   = it >> 1;                  // it 0,1 -> hi ; 2,3 -> lo
        int b     = (chunk & 511) * 16;
        int bs    = b ^ (((b >> 7) & 7) << 4);
        const unsigned short* sp = reg ? Wlo : Whi;
        u32x4 d = *(const u32x4*)((const char*)sp + b);
        *(u32x4*)((char*)Wsh + reg * 8192 + bs) = d;
    }
    // ---- stage block's 32 U rows (contiguous 4 KB) ---------------------
    *(u32x4*)((char*)Ush + tid * 16) =
        *(const u32x4*)((const char*)(U + (size_t)nbB * HDIM) + tid * 16);

    int  srcA = src[(size_t)nb * 16 + lane];
    int  srcB = src[(size_t)(nb + 4) * 16 + lane];
    float b2v = b2[lane];

    __syncthreads();     // drains everything; placed BEFORE gather issue

    // ---- issue all V gathers: tile A first (older), then tile B --------
    u32x4 vA0[4], vA1[4], vB0[4], vB1[4];
#pragma unroll
    for (int mt = 0; mt < 4; ++mt) {
        int s_ = __shfl(srcA, mt * 16 + m);
        const u32x4* vp = (const u32x4*)(V + (size_t)s_ * HDIM + quad * 8);
        vA0[mt] = vp[0]; vA1[mt] = vp[4];
    }
#pragma unroll
    for (int mt = 0; mt < 4; ++mt) {
        int s_ = __shfl(srcB, mt * 16 + m);
        const u32x4* vp = (const u32x4*)(V + (size_t)s_ * HDIM + quad * 8);
        vB0[mt] = vp[0]; vB1[mt] = vp[4];
    }

    // ---- tile A (B's 8 gathers remain in flight), then tile B ----------
    FOLD_HALF(vA0, vA1, 0)
    FOLD_HALF(vB0, vB1, 4)
}

// ---------------------------------------------------------------------------
// region mean accumulation (fp16 input)
// ---------------------------------------------------------------------------
__global__ void region_mean_kernel(const unsigned short* __restrict__ h,
                                   const int* __restrict__ labels,
                                   float* __restrict__ qsums, int* __restrict__ qcnt, int N)
{
    __shared__ float ls[8 * 64];
    __shared__ int   lc[8];
    int tid  = threadIdx.x;
    int lane = tid & 63;
    int gw   = (blockIdx.x * blockDim.x + tid) >> 6;
    int tw   = (gridDim.x * blockDim.x) >> 6;

    float acc[8] = {0, 0, 0, 0, 0, 0, 0, 0};
    int   cnt[8] = {0, 0, 0, 0, 0, 0, 0, 0};

    for (int n = gw; n < N; n += tw) {
        int lbl = labels[n];
        float val = hs2f(h[(size_t)n * HDIM + lane]);
#pragma unroll
        for (int r = 0; r < 8; ++r) {
            acc[r] += (lbl == r) ? val : 0.f;
            cnt[r] += (lbl == r) ? 1 : 0;
        }
    }

    if (tid < 8) lc[tid] = 0;
    for (int idx = tid; idx < 512; idx += 256) ls[idx] = 0.f;
    __syncthreads();
#pragma unroll
    for (int r = 0; r < 8; ++r) atomicAdd(&ls[r * 64 + lane], acc[r]);
    if (lane == 0)
#pragma unroll
        for (int r = 0; r < 8; ++r) atomicAdd(&lc[r], cnt[r]);
    __syncthreads();
    for (int idx = tid; idx < 512; idx += 256) atomicAdd(&qsums[idx], ls[idx]);
    if (tid < 8) atomicAdd(&qcnt[tid], lc[tid]);
}

// ---------------------------------------------------------------------------
// tail: fully parallel quotient convs (8 nodes, 32 edges) + pool + linear.
// ---------------------------------------------------------------------------
#define EQ_MAX 64
__global__ void tail_kernel(const float* __restrict__ qsums, const int* __restrict__ qcnt,
                            const int* __restrict__ qei, int Eq,
                            const float* __restrict__ W31, const float* __restrict__ b31,
                            const float* __restrict__ W32, const float* __restrict__ b32,
                            const float* __restrict__ W41, const float* __restrict__ b41,
                            const float* __restrict__ W42, const float* __restrict__ b42,
                            const float* __restrict__ linW, const float* __restrict__ linb,
                            float* __restrict__ out)
{
    __shared__ float qx[512], uu[512], vv[512];
    __shared__ float hr[EQ_MAX * 64], me[EQ_MAX * 64];
    __shared__ __align__(16) float W2s[64 * 64];
    __shared__ int   qes[EQ_MAX], qet[EQ_MAX];
    __shared__ float emb[64];

    int tid = threadIdx.x;
    if (Eq > EQ_MAX) Eq = EQ_MAX;

    if (tid < Eq) { qes[tid] = qei[tid]; qet[tid] = qei[Eq + tid]; }
    for (int idx = tid; idx < 512; idx += 256) {
        int r = idx >> 6;
        int cc = qcnt[r];
        qx[idx] = (cc > 0) ? qsums[idx] / (float)cc : 0.f;
    }
    __syncthreads();

    for (int layer = 0; layer < 2; ++layer) {
        const float* W1p = layer ? W41 : W31;
        const float* b1p = layer ? b41 : b31;
        const float* W2p = layer ? W42 : W32;
        const float* b2p = layer ? b42 : b32;

        for (int idx = tid * 4; idx < 4096; idx += 1024)
            *(fv4*)&W2s[idx] = *(const fv4*)&W2p[idx];

        for (int idx = tid; idx < 512; idx += 256) {
            int t = idx >> 6, c = idx & 63;
            float su = 0.f, sv = 0.f;
#pragma unroll 8
            for (int d = 0; d < 64; ++d) {
                float hv = qx[t * 64 + d];
                float a = W1p[d * 64 + c];
                float b = W1p[(d + 64) * 64 + c];
                su += hv * (a - b);
                sv += hv * b;
            }
            uu[idx] = su + b1p[c];
            vv[idx] = sv;
        }
        __syncthreads();

        for (int idx = tid; idx < Eq * 64; idx += 256) {
            int e = idx >> 6, c = idx & 63;
            hr[idx] = fmaxf(uu[qet[e] * 64 + c] + vv[qes[e] * 64 + c], 0.f);
        }
        __syncthreads();

        {
            int c = tid & 63, e0 = tid >> 6;
            for (int e = e0; e < Eq; e += 4) {
                float acc = 0.f;
#pragma unroll 8
                for (int j = 0; j < 64; ++j)
                    acc += hr[e * 64 + j] * W2s[j * 64 + c];
                me[e * 64 + c] = acc;
            }
        }
        __syncthreads();

        for (int idx = tid; idx < 512; idx += 256) {
            int t = idx >> 6, c = idx & 63;
            float a = -INFINITY;
            for (int e = 0; e < Eq; ++e)
                if (qet[e] == t) a = fmaxf(a, me[e * 64 + c]);
            float vout = (a == -INFINITY) ? 0.f : (a + b2p[c]);
            qx[idx] = fmaxf(vout, 0.f);
        }
        __syncthreads();
    }

    if (tid < 64) {
        float s = 0.f;
        for (int r = 0; r < 8; ++r) s += qx[r * 64 + tid];
        emb[tid] = s;
    }
    __syncthreads();
    if (tid < 8) {
        float o = linb[tid];
        for (int c = 0; c < 64; ++c) o += emb[c] * linW[c * 8 + tid];
        out[tid] = o;
    }
}

// ---------------------------------------------------------------------------
extern "C" void kernel_launch(void* const* d_in, const int* in_sizes, int n_in,
                              void* d_out, int out_size, void* d_ws, size_t ws_size,
                              hipStream_t stream)
{
    const float* x    = (const float*)d_in[0];
    const float* pos  = (const float*)d_in[1];
    const int*   ei   = (const int*)d_in[2];
    const int*   lbl  = (const int*)d_in[3];
    const int*   qei  = (const int*)d_in[4];
    const float* W11 = (const float*)d_in[5];
    const float* b11 = (const float*)d_in[6];
    const float* W12 = (const float*)d_in[7];
    const float* b12 = (const float*)d_in[8];
    const float* W21 = (const float*)d_in[9];
    const float* b21 = (const float*)d_in[10];
    const float* W22 = (const float*)d_in[11];
    const float* b22 = (const float*)d_in[12];
    const float* W31 = (const float*)d_in[13];
    const float* b31 = (const float*)d_in[14];
    const float* W32 = (const float*)d_in[15];
    const float* b32 = (const float*)d_in[16];
    const float* W41 = (const float*)d_in[17];
    const float* b41 = (const float*)d_in[18];
    const float* W42 = (const float*)d_in[19];
    const float* b42 = (const float*)d_in[20];
    const float* linW = (const float*)d_in[21];
    const float* linb = (const float*)d_in[22];

    int N  = in_sizes[0] / 16;          // 100000
    int Eq = in_sizes[4] / 2;           // 32
    const int* src = ei;                // row 0 = src; tgt = repeat(arange(N),16)

    size_t NH = (size_t)N * HDIM;
    unsigned short* hbf = (unsigned short*)d_ws;   // fp16 N*64 (h1, then h2)
    unsigned short* Ub  = hbf + NH;                // fp16 N*64
    unsigned short* Vb  = Ub + NH;                 // fp16 N*64
    unsigned short* w2h1 = Vb + NH;
    unsigned short* w2l1 = w2h1 + 4096;
    unsigned short* w2h2 = w2l1 + 4096;
    unsigned short* w2l2 = w2h2 + 4096;
    unsigned short* wph  = w2l2 + 4096;            // 8192
    unsigned short* wpl  = wph + 8192;             // 8192
    float* qsums = (float*)(wpl + 8192);
    int*   qcnt  = (int*)(qsums + 512);

    int nTiles      = N / 16;           // pre_mfma tiles (6250)
    int edgeBlocks  = N / 32;           // edge blocks, 32 nodes each (3125)
    int mainBlocks  = 2048;

    // conv1 (pre1 + fused prep + qsums zeroing)
    pre1_kernel<<<mainBlocks + 32, 256, 0, stream>>>(
        x, pos, W11, b11, Ub, Vb, N, mainBlocks,
        W12, W22, W21, w2h1, w2l1, w2h2, w2l2, wph, wpl, (int*)qsums);
    edge_mfma_kernel<<<edgeBlocks, 256, 0, stream>>>(Ub, Vb, src, w2h1, w2l1, b12, hbf);
    // conv2
    pre_mfma_kernel<<<512, 256, 0, stream>>>(hbf, wph, wpl, b21, Ub, Vb, nTiles);
    edge_mfma_kernel<<<edgeBlocks, 256, 0, stream>>>(Ub, Vb, src, w2h2, w2l2, b22, hbf);
    // quotient pooling + tail
    region_mean_kernel<<<1024, 256, 0, stream>>>(hbf, lbl, qsums, qcnt, N);
    tail_kernel<<<1, 256, 0, stream>>>(qsums, qcnt, qei, Eq,
                                       W31, b31, W32, b32,
                                       W41, b41, W42, b42,
                                       linW, linb, (float*)d_out);
}